// Round 1
// baseline (191.277 us; speedup 1.0000x reference)
//
#include <hip/hip_runtime.h>

// Problem constants (fixed by the reference)
constexpr int B  = 8;
constexpr int N  = 1024;
constexpr int FI = 64;    // F_in
constexpr int FO = 128;   // F_out
constexpr int NH = 4;     // heads
constexpr float SLOPE = 0.2f;

__device__ __forceinline__ float lrelu(float x) { return x > 0.f ? x : SLOPE * x; }

// ---------------------------------------------------------------------------
// Kernel 1: h = x @ W  -> hmat [B*N, 128] (row-major, f = head*32 + d)
//           e_src[row,h] = sum_d h* a[h, d], e_dst[row,h] = sum_d h*a[h, 32+d]
// Block: 256 threads, 32 rows. W column held in 64 VGPRs (coalesced global
// loads, L2-hot); x tile in LDS read via broadcast b128 (conflict-free).
// ---------------------------------------------------------------------------
__global__ __launch_bounds__(256) void gat_proj(
    const float* __restrict__ x, const float* __restrict__ W,
    const float* __restrict__ a, float* __restrict__ hmat,
    float* __restrict__ es, float* __restrict__ ed) {
  __shared__ float xs[32 * FI];
  const int t = threadIdx.x;
  const int row0 = blockIdx.x * 32;
  for (int i = t; i < 32 * FI; i += 256) xs[i] = x[row0 * FI + i];
  const int f  = t & 127;
  const int rh = t >> 7;              // 0/1 -> rows rh*16..+16
  float wc[FI];
  #pragma unroll
  for (int k = 0; k < FI; ++k) wc[k] = W[k * FO + f];
  const int hh = f >> 5, d = f & 31;
  const float a_s = a[hh * 64 + d];
  const float a_d = a[hh * 64 + 32 + d];
  __syncthreads();
  for (int r = 0; r < 16; ++r) {
    const int lr = rh * 16 + r;
    const float4* xr = (const float4*)(xs + lr * FI);
    float acc = 0.f;
    #pragma unroll
    for (int kq = 0; kq < FI / 4; ++kq) {
      const float4 xv = xr[kq];
      acc += xv.x * wc[4*kq] + xv.y * wc[4*kq+1] + xv.z * wc[4*kq+2] + xv.w * wc[4*kq+3];
    }
    const int row = row0 + lr;
    hmat[row * FO + f] = acc;
    // per-head reductions over the 32 d-lanes (lane groups are 32-aligned)
    float ps = acc * a_s, pd = acc * a_d;
    #pragma unroll
    for (int off = 16; off; off >>= 1) {
      ps += __shfl_xor(ps, off, 64);
      pd += __shfl_xor(pd, off, 64);
    }
    if (d == 0) { es[row * NH + hh] = ps; ed[row * NH + hh] = pd; }
  }
}

// ---------------------------------------------------------------------------
// Kernel 2: per (b, 16-row i-tile): denom[h] = sum_j exp(e), and
//           out[i,f] = (1/denom) * sum_j p*ew*h[b,j,f].
// P1: 256 thr = 64 j x 4 row-groups compute pew tile (64 s x 64 j) into LDS
//     (XOR-swizzled so P2's b128 reads are <=2-way on banks).
// P2: thread = (fq 16 x rg 2 x jg 8): 8 rows x 8 f register outer product,
//     1 ds_read_b128 per 16 FMAs, h loads reused across 8 rows.
// ---------------------------------------------------------------------------
__global__ __launch_bounds__(256) void gat_attn(
    const float* __restrict__ hmat, const float* __restrict__ es,
    const float* __restrict__ ed, const int* __restrict__ adj,
    const float* __restrict__ ew, float* __restrict__ out,
    float* __restrict__ dinvw) {
  __shared__ float smem[8192];   // pew tile (first 4096) UNION scratch[4][16][128]
  __shared__ float esl[64];
  __shared__ float dvl[64];
  const int t  = threadIdx.x;
  const int b  = blockIdx.x >> 6;
  const int i0 = (blockIdx.x & 63) << 4;
  if (t < 64) esl[t] = es[(b * N + i0) * NH + t];
  // P1 ids
  const int jj = t & 63, tg = t >> 6;
  // P2 ids
  const int fq = t & 15, rg = (t >> 4) & 1, jg = t >> 5;
  const int h2 = fq >> 2;  // head of this thread's f-octet
  float dpart[16];
  float acc[64];
  #pragma unroll
  for (int i = 0; i < 16; ++i) dpart[i] = 0.f;
  #pragma unroll
  for (int i = 0; i < 64; ++i) acc[i] = 0.f;
  __syncthreads();

  for (int tile = 0; tile < N / 64; ++tile) {
    const int j0 = tile * 64;
    // ---- P1: pew tile + denominator partials ----
    {
      const int j = j0 + jj;
      const float4 e4 = *(const float4*)(ed + (b * N + j) * NH);
      const float edh[4] = {e4.x, e4.y, e4.z, e4.w};
      #pragma unroll
      for (int c = 0; c < 4; ++c) {
        const int ti = tg * 4 + c;
        const int gi = i0 + ti;
        const int av    = adj[gi * N + j];
        const float eww = ew[gi * N + j];
        #pragma unroll
        for (int hh = 0; hh < NH; ++hh) {
          const float e = lrelu(esl[ti * NH + hh] + edh[hh]);
          const float p = av ? __expf(e) : 0.f;   // masked ref term exp(-100) ~ 3.7e-44: negligible
          dpart[c * 4 + hh] += p;
          const int s = ti * 4 + hh;
          const int m = (s & 15) ^ ((s >> 5) << 3);
          smem[s * 64 + (((jj >> 2) ^ m) & 15) * 4 + (jj & 3)] = p * eww;
        }
      }
    }
    __syncthreads();
    // ---- P2: register outer-product PV ----
    #pragma unroll
    for (int q = 0; q < 2; ++q) {
      const int jl = jg * 8 + q * 4;
      const int jb = b * N + j0 + jl;
      float hv[4][8];
      #pragma unroll
      for (int c = 0; c < 4; ++c) {
        const float4 h0 = *(const float4*)(hmat + (jb + c) * FO + fq * 8);
        const float4 h1 = *(const float4*)(hmat + (jb + c) * FO + fq * 8 + 4);
        hv[c][0]=h0.x; hv[c][1]=h0.y; hv[c][2]=h0.z; hv[c][3]=h0.w;
        hv[c][4]=h1.x; hv[c][5]=h1.y; hv[c][6]=h1.z; hv[c][7]=h1.w;
      }
      const int j4 = jl >> 2;
      #pragma unroll
      for (int rr = 0; rr < 8; ++rr) {
        const int s = (rg * 8 + rr) * 4 + h2;
        const int m = (s & 15) ^ ((s >> 5) << 3);
        const float4 p4 = *(const float4*)(smem + s * 64 + ((j4 ^ m) & 15) * 4);
        const float pc[4] = {p4.x, p4.y, p4.z, p4.w};
        #pragma unroll
        for (int c = 0; c < 4; ++c) {
          #pragma unroll
          for (int ff = 0; ff < 8; ++ff)
            acc[rr * 8 + ff] += pc[c] * hv[c][ff];
        }
      }
    }
    __syncthreads();
  }

  // merge the two jg halves living in the same wave
  #pragma unroll
  for (int i = 0; i < 64; ++i) acc[i] += __shfl_xor(acc[i], 32, 64);
  // lanes<32 of each wave write their (16 x 128) partial to scratch
  const int w = t >> 6;
  if ((t & 63) < 32) {
    #pragma unroll
    for (int rr = 0; rr < 8; ++rr) {
      const int ti = rg * 8 + rr;
      const float4 v0 = {acc[rr*8+0], acc[rr*8+1], acc[rr*8+2], acc[rr*8+3]};
      const float4 v1 = {acc[rr*8+4], acc[rr*8+5], acc[rr*8+6], acc[rr*8+7]};
      *(float4*)(smem + w * 2048 + ti * FO + fq * 8)     = v0;
      *(float4*)(smem + w * 2048 + ti * FO + fq * 8 + 4) = v1;
    }
  }
  // denominator reduce: wave tg owns rows tg*4..+4 (all h)
  #pragma unroll
  for (int i = 0; i < 16; ++i) {
    float v = dpart[i];
    #pragma unroll
    for (int off = 32; off; off >>= 1) v += __shfl_xor(v, off, 64);
    if ((t & 63) == 0) dvl[tg * 16 + i] = v;
  }
  __syncthreads();
  if (t < 64) {
    const float inv = 1.0f / dvl[t];
    dvl[t] = inv;
    dinvw[(b * N + i0) * NH + t] = inv;
  }
  __syncthreads();
  // final: sum 4 wave-partials, normalize, store
  {
    const int f = t & 127, g2 = t >> 7;
    #pragma unroll
    for (int k = 0; k < 8; ++k) {
      const int ti = g2 * 8 + k;
      float sum = smem[ti * FO + f] + smem[2048 + ti * FO + f]
                + smem[4096 + ti * FO + f] + smem[6144 + ti * FO + f];
      sum *= dvl[ti * NH + (f >> 5)];
      out[(b * N + i0 + ti) * FO + f] = sum;
    }
  }
}

// ---------------------------------------------------------------------------
// Kernel 3: avg_attn[b,i,j] = ew[i,j]/4 * sum_h exp(e)/denom_h (recompute exp)
// ---------------------------------------------------------------------------
__global__ __launch_bounds__(256) void gat_avg(
    const float* __restrict__ es, const float* __restrict__ ed,
    const int* __restrict__ adj, const float* __restrict__ ew,
    const float* __restrict__ dinvw, float* __restrict__ avg) {
  __shared__ float esl[64], dvl[64];
  const int t  = threadIdx.x;
  const int b  = blockIdx.x >> 6;
  const int i0 = (blockIdx.x & 63) << 4;
  if (t < 64) {
    esl[t] = es[(b * N + i0) * NH + t];
    dvl[t] = dinvw[(b * N + i0) * NH + t];
  }
  __syncthreads();
  #pragma unroll
  for (int rep = 0; rep < 4; ++rep) {
    const int j = rep * 256 + t;
    const float4 e4 = *(const float4*)(ed + (b * N + j) * NH);
    const float edh[4] = {e4.x, e4.y, e4.z, e4.w};
    #pragma unroll 4
    for (int ti = 0; ti < 16; ++ti) {
      const int gi = i0 + ti;
      const int av    = adj[gi * N + j];
      const float eww = ew[gi * N + j];
      float s = 0.f;
      #pragma unroll
      for (int hh = 0; hh < NH; ++hh) {
        const float e = lrelu(esl[ti * NH + hh] + edh[hh]);
        s += __expf(e) * dvl[ti * NH + hh];
      }
      avg[(b * N + gi) * N + j] = av ? 0.25f * eww * s : 0.f;
    }
  }
}

// ---------------------------------------------------------------------------
extern "C" void kernel_launch(void* const* d_in, const int* in_sizes, int n_in,
                              void* d_out, int out_size, void* d_ws, size_t ws_size,
                              hipStream_t stream) {
  const float* x   = (const float*)d_in[0];
  const int*   adj = (const int*)d_in[1];
  const float* ewt = (const float*)d_in[2];
  const float* W   = (const float*)d_in[3];
  const float* a   = (const float*)d_in[4];

  float* out = (float*)d_out;                 // [B,N,128]
  float* avg = out + (size_t)B * N * FO;      // [B,N,N]

  float* hbuf = (float*)d_ws;                 // [B*N,128]  4 MB
  float* es   = hbuf + (size_t)B * N * FO;    // [B*N,4]
  float* ed   = es + (size_t)B * N * NH;      // [B*N,4]
  float* dinv = ed + (size_t)B * N * NH;      // [B*N,4]

  gat_proj<<<(B * N) / 32, 256, 0, stream>>>(x, W, a, hbuf, es, ed);
  gat_attn<<<B * (N / 16), 256, 0, stream>>>(hbuf, es, ed, adj, ewt, out, dinv);
  gat_avg <<<B * (N / 16), 256, 0, stream>>>(es, ed, adj, ewt, dinv, avg);
}

// Round 2
// 179.013 us; speedup vs baseline: 1.0685x; 1.0685x over previous
//
#include <hip/hip_runtime.h>

// Problem constants (fixed by the reference)
constexpr int B  = 8;
constexpr int N  = 1024;
constexpr int FI = 64;    // F_in
constexpr int FO = 128;   // F_out
constexpr int NH = 4;     // heads
constexpr float SLOPE = 0.2f;

__device__ __forceinline__ float lrelu(float x) { return x > 0.f ? x : SLOPE * x; }

// ---------------------------------------------------------------------------
// Kernel 1: h = x @ W -> hmat [B*N,128]; es/ed per-head attention logits.
// 16 rows/block -> 512 blocks (2/CU, 2 waves/SIMD). 2-row unroll for ILP.
// ---------------------------------------------------------------------------
__global__ __launch_bounds__(256) void gat_proj(
    const float* __restrict__ x, const float* __restrict__ W,
    const float* __restrict__ a, float* __restrict__ hmat,
    float* __restrict__ es, float* __restrict__ ed) {
  __shared__ float xs[16 * FI];
  const int t = threadIdx.x;
  const int row0 = blockIdx.x * 16;
  for (int i = t; i < 16 * FI; i += 256) xs[i] = x[row0 * FI + i];
  const int f  = t & 127;
  const int rh = t >> 7;              // 0/1 -> rows rh*8..+8
  float wc[FI];
  #pragma unroll
  for (int k = 0; k < FI; ++k) wc[k] = W[k * FO + f];
  const int hh = f >> 5, d = f & 31;
  const float a_s = a[hh * 64 + d];
  const float a_d = a[hh * 64 + 32 + d];
  __syncthreads();
  #pragma unroll 2
  for (int r = 0; r < 8; ++r) {
    const int lr = rh * 8 + r;
    const float4* xr = (const float4*)(xs + lr * FI);
    float acc = 0.f;
    #pragma unroll
    for (int kq = 0; kq < FI / 4; ++kq) {
      const float4 xv = xr[kq];
      acc += xv.x * wc[4*kq] + xv.y * wc[4*kq+1] + xv.z * wc[4*kq+2] + xv.w * wc[4*kq+3];
    }
    const int row = row0 + lr;
    hmat[row * FO + f] = acc;
    float ps = acc * a_s, pd = acc * a_d;   // reduce over the 32 d-lanes
    #pragma unroll
    for (int off = 16; off; off >>= 1) {
      ps += __shfl_xor(ps, off, 64);
      pd += __shfl_xor(pd, off, 64);
    }
    if (d == 0) { es[row * NH + hh] = ps; ed[row * NH + hh] = pd; }
  }
}

// ---------------------------------------------------------------------------
// Kernel 2 (fused attn + avg_attn): per (b, 8-row i-tile):
//  main loop over 16 j-tiles of 64:
//   P1: 64 j x 4 tg x 2 rows -> pew tile (32 s x 64 j) in LDS, denom partials
//   P2: thread = fq(16) x jg(16): 8 rows x 8 f register outer product over 4 j
//  pipelined: hv global loads issued before P1 compute; next tile's
//  adj/ew/ed prefetched during P2.
//  epilogue: reduce, write out, then avg pass (adj/ew L2-hot, denom in LDS).
// ---------------------------------------------------------------------------
__global__ __launch_bounds__(256, 4) void gat_attn(
    const float* __restrict__ hmat, const float* __restrict__ es,
    const float* __restrict__ ed, const int* __restrict__ adj,
    const float* __restrict__ ew, float* __restrict__ out,
    float* __restrict__ avg) {
  __shared__ float smem[4096];   // pew tile (2048) UNION scratch[4][8][128]
  __shared__ float esl[32];
  __shared__ float dvl[32];
  const int t  = threadIdx.x;
  const int b  = blockIdx.x >> 7;
  const int i0 = (blockIdx.x & 127) << 3;
  if (t < 32) esl[t] = es[(b * N + i0) * NH + t];
  // P1 ids
  const int jj = t & 63, tg = t >> 6;       // tg owns rows tg*2, tg*2+1
  // P2 ids
  const int fq = t & 15, jg = t >> 4;       // jg owns j-quad jg
  const int h2 = fq >> 2;                   // head of this thread's f-octet
  float dpart[8];
  float acc[64];
  #pragma unroll
  for (int i = 0; i < 8; ++i) dpart[i] = 0.f;
  #pragma unroll
  for (int i = 0; i < 64; ++i) acc[i] = 0.f;
  __syncthreads();

  // preload tile-0 P1 inputs
  const int r0 = i0 + tg * 2;
  float4 edc = *(const float4*)(ed + (b * N + jj) * NH);
  int   av0 = adj[r0 * N + jj],       av1 = adj[(r0 + 1) * N + jj];
  float ew0 = ew[r0 * N + jj],        ew1 = ew[(r0 + 1) * N + jj];

  for (int tile = 0; tile < N / 64; ++tile) {
    const int j0 = tile * 64;
    // issue hv global loads early (independent of P1 / LDS)
    float4 hv4[8];
    {
      const int jb = b * N + j0 + jg * 4;
      #pragma unroll
      for (int c = 0; c < 4; ++c) {
        hv4[2*c]   = *(const float4*)(hmat + (jb + c) * FO + fq * 8);
        hv4[2*c+1] = *(const float4*)(hmat + (jb + c) * FO + fq * 8 + 4);
      }
    }
    // ---- P1 from preloaded regs ----
    {
      const float edh[4] = {edc.x, edc.y, edc.z, edc.w};
      #pragma unroll
      for (int c = 0; c < 2; ++c) {
        const int ti = tg * 2 + c;
        const int av    = c ? av1 : av0;
        const float eww = c ? ew1 : ew0;
        #pragma unroll
        for (int hh = 0; hh < NH; ++hh) {
          const float e = lrelu(esl[ti * NH + hh] + edh[hh]);
          const float p = av ? __expf(e) : 0.f;  // masked exp(-100)~3.7e-44: negligible
          dpart[c * 4 + hh] += p;
          const int s  = ti * NH + hh;
          const int cg = ((jj >> 2) ^ (2 * (s & 3))) & 15;  // bank swizzle
          smem[s * 64 + cg * 4 + (jj & 3)] = p * eww;
        }
      }
    }
    __syncthreads();
    // prefetch next tile's P1 inputs (overlaps P2 compute)
    if (tile + 1 < N / 64) {
      const int jn = j0 + 64 + jj;
      edc = *(const float4*)(ed + (b * N + jn) * NH);
      av0 = adj[r0 * N + jn];  av1 = adj[(r0 + 1) * N + jn];
      ew0 = ew[r0 * N + jn];   ew1 = ew[(r0 + 1) * N + jn];
    }
    // ---- P2: register outer-product PV ----
    #pragma unroll
    for (int rr = 0; rr < 8; ++rr) {
      const int s  = rr * NH + h2;
      const int cg = (jg ^ (2 * (s & 3))) & 15;
      const float4 p4 = *(const float4*)(smem + s * 64 + cg * 4);
      const float pc[4] = {p4.x, p4.y, p4.z, p4.w};
      #pragma unroll
      for (int c = 0; c < 4; ++c) {
        const float* hv = (const float*)&hv4[2*c];
        #pragma unroll
        for (int ff = 0; ff < 8; ++ff)
          acc[rr * 8 + ff] += pc[c] * hv[ff];
      }
    }
    __syncthreads();
  }

  // merge the 4 jg quads living in the same wave
  #pragma unroll
  for (int i = 0; i < 64; ++i) {
    acc[i] += __shfl_xor(acc[i], 16, 64);
    acc[i] += __shfl_xor(acc[i], 32, 64);
  }
  // lanes 0..15 of each wave write their (8 x 128) partial to scratch
  const int w = t >> 6;
  if ((t & 48) == 0) {
    #pragma unroll
    for (int rr = 0; rr < 8; ++rr) {
      const float4 v0 = {acc[rr*8+0], acc[rr*8+1], acc[rr*8+2], acc[rr*8+3]};
      const float4 v1 = {acc[rr*8+4], acc[rr*8+5], acc[rr*8+6], acc[rr*8+7]};
      *(float4*)(smem + w * 1024 + rr * FO + fq * 8)     = v0;
      *(float4*)(smem + w * 1024 + rr * FO + fq * 8 + 4) = v1;
    }
  }
  // denominator reduce: wave tg holds rows tg*2..+2 (all h), reduce over jj
  #pragma unroll
  for (int i = 0; i < 8; ++i) {
    float v = dpart[i];
    #pragma unroll
    for (int off = 32; off; off >>= 1) v += __shfl_xor(v, off, 64);
    if (jj == 0) dvl[tg * 8 + i] = v;
  }
  __syncthreads();
  if (t < 32) dvl[t] = 1.0f / dvl[t];
  __syncthreads();
  // final out: sum 4 wave-partials, normalize, store
  {
    const int f = t & 127, g2 = t >> 7;
    #pragma unroll
    for (int k = 0; k < 4; ++k) {
      const int ti = g2 * 4 + k;
      float sum = smem[ti * FO + f] + smem[1024 + ti * FO + f]
                + smem[2048 + ti * FO + f] + smem[3072 + ti * FO + f];
      sum *= dvl[ti * NH + (f >> 5)];
      out[(b * N + i0 + ti) * FO + f] = sum;
    }
  }
  // ---- fused avg_attn pass (adj/ew rows are L1/L2-hot from P1) ----
  #pragma unroll
  for (int rep = 0; rep < 4; ++rep) {
    const int j = rep * 256 + t;
    const float4 e4 = *(const float4*)(ed + (b * N + j) * NH);
    const float edh[4] = {e4.x, e4.y, e4.z, e4.w};
    #pragma unroll
    for (int ti = 0; ti < 8; ++ti) {
      const int gi = i0 + ti;
      const int av    = adj[gi * N + j];
      const float eww = ew[gi * N + j];
      float sv = 0.f;
      #pragma unroll
      for (int hh = 0; hh < NH; ++hh) {
        const float e = lrelu(esl[ti * NH + hh] + edh[hh]);
        sv += __expf(e) * dvl[ti * NH + hh];
      }
      avg[(b * N + gi) * N + j] = av ? 0.25f * eww * sv : 0.f;
    }
  }
}

// ---------------------------------------------------------------------------
extern "C" void kernel_launch(void* const* d_in, const int* in_sizes, int n_in,
                              void* d_out, int out_size, void* d_ws, size_t ws_size,
                              hipStream_t stream) {
  const float* x   = (const float*)d_in[0];
  const int*   adj = (const int*)d_in[1];
  const float* ewt = (const float*)d_in[2];
  const float* W   = (const float*)d_in[3];
  const float* a   = (const float*)d_in[4];

  float* out = (float*)d_out;                 // [B,N,128]
  float* avg = out + (size_t)B * N * FO;      // [B,N,N]

  float* hbuf = (float*)d_ws;                 // [B*N,128]  4 MB
  float* es   = hbuf + (size_t)B * N * FO;    // [B*N,4]
  float* ed   = es + (size_t)B * N * NH;      // [B*N,4]

  gat_proj<<<(B * N) / 16, 256, 0, stream>>>(x, W, a, hbuf, es, ed);
  gat_attn<<<B * (N / 8), 256, 0, stream>>>(hbuf, es, ed, adj, ewt, out, avg);
}

// Round 3
// 141.683 us; speedup vs baseline: 1.3500x; 1.2635x over previous
//
#include <hip/hip_runtime.h>
#include <hip/hip_bf16.h>

constexpr int B  = 8;
constexpr int N  = 1024;
constexpr int FI = 64;
constexpr int FO = 128;
constexpr int NH = 4;
constexpr float LOG2E = 1.4426950408889634f;

using short8 = __attribute__((ext_vector_type(8))) short;
using f32x4  = __attribute__((ext_vector_type(4))) float;

union I8 { int4 v[2]; int s[8]; };
union F8 { float4 v[2]; float s[8]; };

__device__ __forceinline__ unsigned bfpack(float a, float b) {
  __hip_bfloat162 r = __float22bfloat162_rn(make_float2(a, b));
  union { __hip_bfloat162 h; unsigned u; } c; c.h = r; return c.u;
}

// ---------------------------------------------------------------------------
// Kernel 1: h = x@W. Emits es/ed (pre-scaled by log2e) and h transposed
// bf16 split hi/lo: h_t[b][f][j] so attn's MFMA B-frags are 16B/lane loads.
// ---------------------------------------------------------------------------
__global__ __launch_bounds__(256, 2) void gat_proj(
    const float* __restrict__ x, const float* __restrict__ W,
    const float* __restrict__ a,
    unsigned short* __restrict__ h_hi, unsigned short* __restrict__ h_lo,
    float* __restrict__ es, float* __restrict__ ed) {
  __shared__ float xs[16 * FI];
  const int t = threadIdx.x;
  const int row0 = blockIdx.x * 16;
  for (int i = t; i < 16 * FI; i += 256) xs[i] = x[row0 * FI + i];
  const int f  = t & 127;
  const int rh = t >> 7;              // rows rh*8 .. rh*8+7
  float wc[FI];
  #pragma unroll
  for (int k = 0; k < FI; ++k) wc[k] = W[k * FO + f];
  const int hh = f >> 5, d = f & 31;
  const float a_s = a[hh * 64 + d] * LOG2E;        // bake log2e into logits
  const float a_d = a[hh * 64 + 32 + d] * LOG2E;
  __syncthreads();
  float acc8[8];
  #pragma unroll
  for (int r = 0; r < 8; ++r) {
    const int lr = rh * 8 + r;
    const float4* xr = (const float4*)(xs + lr * FI);
    float acc = 0.f;
    #pragma unroll
    for (int kq = 0; kq < FI / 4; ++kq) {
      const float4 xv = xr[kq];
      acc += xv.x * wc[4*kq] + xv.y * wc[4*kq+1] + xv.z * wc[4*kq+2] + xv.w * wc[4*kq+3];
    }
    acc8[r] = acc;
    float ps = acc * a_s, pd = acc * a_d;  // reduce over 32 d-lanes
    #pragma unroll
    for (int off = 16; off; off >>= 1) {
      ps += __shfl_xor(ps, off, 64);
      pd += __shfl_xor(pd, off, 64);
    }
    const int row = row0 + lr;
    if (d == 0) { es[row * NH + hh] = ps; ed[row * NH + hh] = pd; }
  }
  // transposed bf16 hi/lo stores: h_t[b][f][j], 8 consecutive j per thread
  const int bb = row0 >> 10;
  const int jl = (row0 & 1023) + rh * 8;
  union { unsigned short u16[8]; uint4 v; } hi, lo;
  #pragma unroll
  for (int r = 0; r < 8; ++r) {
    __hip_bfloat16 hb = __float2bfloat16(acc8[r]);
    hi.u16[r] = *reinterpret_cast<unsigned short*>(&hb);
    float res = acc8[r] - __bfloat162float(hb);
    __hip_bfloat16 lb = __float2bfloat16(res);
    lo.u16[r] = *reinterpret_cast<unsigned short*>(&lb);
  }
  const size_t base = ((size_t)(bb * FO + f)) * N + jl;
  *(uint4*)(h_hi + base) = hi.v;
  *(uint4*)(h_lo + base) = lo.v;
}

// ---------------------------------------------------------------------------
// Kernel 2: fused attention + avg. Per (b, 16-row tile):
//  pre: stage ed row-block (swizzled) in LDS; es in regs.
//  chunk loop (8 x 128 j): P1 exp2->pew bf16 in A-frag layout (LDS, swizzled);
//  P2: per-wave (head) MFMA 16x16x32_bf16, B hi/lo direct from global h_t.
//  epi: denom reduce -> inv; normalized D stores; avg pass recomputing exp.
// ---------------------------------------------------------------------------
__global__ __launch_bounds__(256, 4) void gat_attn(
    const unsigned short* __restrict__ h_hi, const unsigned short* __restrict__ h_lo,
    const float* __restrict__ es, const float* __restrict__ ed,
    const int* __restrict__ adj, const float* __restrict__ ew,
    float* __restrict__ out, float* __restrict__ avg) {
  __shared__ float edl[4096];           // [j][h] fp32, j low3 xor-swizzled
  __shared__ unsigned short pew[8192];  // 4 heads x 2048, A-frag layout, swizzled
  __shared__ float dvl[64];
  const int t  = threadIdx.x;
  const int b  = blockIdx.x & 7;            // b-clustered per XCD
  const int i0 = (blockIdx.x >> 3) << 4;
  // stage ed (swizzled so P1's 16-address read pattern is 2-way max)
  #pragma unroll
  for (int rep = 0; rep < 4; ++rep) {
    const int j = rep * 256 + t;
    const float4 e4 = *(const float4*)(ed + ((size_t)b * N + j) * NH);
    const int jp = j ^ ((j >> 3) & 7);
    *(float4*)(edl + jp * 4) = e4;
  }
  // P1/avg ids
  const int il = t >> 4, joct = t & 15;
  const int gi = i0 + il;
  float esv[4];
  { const float4 e4 = *(const float4*)(es + ((size_t)b * N + gi) * NH);
    esv[0] = e4.x; esv[1] = e4.y; esv[2] = e4.z; esv[3] = e4.w; }
  // P2 ids
  const int wave = t >> 6, lane = t & 63;
  const int m = lane & 15, kq = lane >> 4;
  const int fn0 = wave * 32;
  f32x4 acc[2] = {{0.f,0.f,0.f,0.f},{0.f,0.f,0.f,0.f}};
  float dpart[4] = {0.f, 0.f, 0.f, 0.f};
  __syncthreads();

  for (int c = 0; c < 8; ++c) {
    const int j0 = c * 128;
    // ---- P1: p = exp2(lrelu(es'+ed')), pack bf16 into A-frag LDS ----
    {
      const int jb = j0 + joct * 8;
      I8 aj; aj.v[0] = *(const int4*)(adj + (size_t)gi * N + jb);
             aj.v[1] = *(const int4*)(adj + (size_t)gi * N + jb + 4);
      F8 ee; ee.v[0] = *(const float4*)(ew + (size_t)gi * N + jb);
             ee.v[1] = *(const float4*)(ew + (size_t)gi * N + jb + 4);
      const int s3 = joct & 7;
      float pw[4][8];
      #pragma unroll
      for (int u = 0; u < 8; ++u) {
        const float4 edv = *(const float4*)(edl + (jb + (u ^ s3)) * 4);
        const float ev[4] = {edv.x, edv.y, edv.z, edv.w};
        const int av = aj.s[u];
        const float eww = ee.s[u];
        #pragma unroll
        for (int h = 0; h < 4; ++h) {
          float e = esv[h] + ev[h];
          e = fmaxf(e, 0.2f * e);                 // lrelu (scale-commutes)
          float p = __builtin_amdgcn_exp2f(e);
          p = av ? p : 0.f;                        // masked: exp(-100)~0
          dpart[h] += p;
          pw[h][u] = p * eww;
        }
      }
      const int o0 = ((joct * 16 + il) ^ (joct & 7)) * 8;
      #pragma unroll
      for (int h = 0; h < 4; ++h) {
        uint4 pk;
        pk.x = bfpack(pw[h][0], pw[h][1]);
        pk.y = bfpack(pw[h][2], pw[h][3]);
        pk.z = bfpack(pw[h][4], pw[h][5]);
        pk.w = bfpack(pw[h][6], pw[h][7]);
        *(uint4*)(pew + h * 2048 + o0) = pk;
      }
    }
    __syncthreads();
    // ---- P2: MFMA, B-frags straight from global (L2-hot h_t) ----
    #pragma unroll
    for (int ks = 0; ks < 4; ++ks) {
      const int g = ks * 4 + kq;
      const int o = ((g * 16 + m) ^ (g & 7)) * 8;
      short8 afr;
      { uint4 tmp = *(const uint4*)(pew + wave * 2048 + o);
        __builtin_memcpy(&afr, &tmp, 16); }
      const int jc = j0 + ks * 32 + kq * 8;
      #pragma unroll
      for (int nt = 0; nt < 2; ++nt) {
        const size_t boff = ((size_t)(b * FO + fn0 + nt * 16 + m)) * N + jc;
        const short8 bhi = *(const short8*)(h_hi + boff);
        const short8 blo = *(const short8*)(h_lo + boff);
        acc[nt] = __builtin_amdgcn_mfma_f32_16x16x32_bf16(afr, bhi, acc[nt], 0, 0, 0);
        acc[nt] = __builtin_amdgcn_mfma_f32_16x16x32_bf16(afr, blo, acc[nt], 0, 0, 0);
      }
    }
    __syncthreads();
  }

  // ---- denominators: 16 lanes sharing il reduce over joct ----
  #pragma unroll
  for (int h = 0; h < 4; ++h) {
    float v = dpart[h];
    v += __shfl_xor(v, 1, 64); v += __shfl_xor(v, 2, 64);
    v += __shfl_xor(v, 4, 64); v += __shfl_xor(v, 8, 64);
    if (joct == 0) dvl[il * NH + h] = v;
  }
  __syncthreads();
  if (t < 64) { const float dd = dvl[t]; dvl[t] = dd > 0.f ? 1.0f / dd : 0.f; }
  __syncthreads();
  // ---- epilogue: normalize D, store out ----
  #pragma unroll
  for (int nt = 0; nt < 2; ++nt) {
    #pragma unroll
    for (int reg = 0; reg < 4; ++reg) {
      const int row = kq * 4 + reg;                 // D: col=lane&15, row=quad*4+reg
      const float inv = dvl[row * NH + wave];
      out[((size_t)b * N + i0 + row) * FO + fn0 + nt * 16 + m] = acc[nt][reg] * inv;
    }
  }
  // ---- avg pass: recompute p, scale by inv, write [b,i,j] ----
  float inv4[4];
  #pragma unroll
  for (int h = 0; h < 4; ++h) inv4[h] = dvl[il * NH + h];
  for (int c = 0; c < 8; ++c) {
    const int jb = c * 128 + joct * 8;
    I8 aj; aj.v[0] = *(const int4*)(adj + (size_t)gi * N + jb);
           aj.v[1] = *(const int4*)(adj + (size_t)gi * N + jb + 4);
    F8 ee; ee.v[0] = *(const float4*)(ew + (size_t)gi * N + jb);
           ee.v[1] = *(const float4*)(ew + (size_t)gi * N + jb + 4);
    const int s3 = joct & 7;
    F8 r8;
    #pragma unroll
    for (int u = 0; u < 8; ++u) {
      const float4 edv = *(const float4*)(edl + (jb + (u ^ s3)) * 4);
      const float ev[4] = {edv.x, edv.y, edv.z, edv.w};
      float sv = 0.f;
      #pragma unroll
      for (int h = 0; h < 4; ++h) {
        float e = esv[h] + ev[h];
        e = fmaxf(e, 0.2f * e);
        sv += __builtin_amdgcn_exp2f(e) * inv4[h];
      }
      r8.s[u] = aj.s[u] ? 0.25f * ee.s[u] * sv : 0.f;
    }
    float* dst = avg + ((size_t)b * N + gi) * N + jb;
    *(float4*)dst       = r8.v[0];
    *(float4*)(dst + 4) = r8.v[1];
  }
}

// ---------------------------------------------------------------------------
extern "C" void kernel_launch(void* const* d_in, const int* in_sizes, int n_in,
                              void* d_out, int out_size, void* d_ws, size_t ws_size,
                              hipStream_t stream) {
  const float* x   = (const float*)d_in[0];
  const int*   adj = (const int*)d_in[1];
  const float* ewt = (const float*)d_in[2];
  const float* W   = (const float*)d_in[3];
  const float* a   = (const float*)d_in[4];

  float* out = (float*)d_out;                  // [B,N,128]
  float* avg = out + (size_t)B * N * FO;       // [B,N,N]

  unsigned short* hhi = (unsigned short*)d_ws;       // [B*FO, N] bf16, 2 MB
  unsigned short* hlo = hhi + (size_t)B * FO * N;    // residual, 2 MB
  float* es = (float*)(hlo + (size_t)B * FO * N);    // [B*N, 4]
  float* ed = es + (size_t)B * N * NH;               // [B*N, 4]

  gat_proj<<<(B * N) / 16, 256, 0, stream>>>(x, W, a, hhi, hlo, es, ed);
  gat_attn<<<B * (N / 16), 256, 0, stream>>>(hhi, hlo, es, ed, adj, ewt, out, avg);
}

// Round 4
// 131.886 us; speedup vs baseline: 1.4503x; 1.0743x over previous
//
#include <hip/hip_runtime.h>
#include <hip/hip_bf16.h>

constexpr int B  = 8;
constexpr int N  = 1024;
constexpr int FI = 64;
constexpr int FO = 128;
constexpr int NH = 4;
constexpr float LOG2E = 1.4426950408889634f;

using short8 = __attribute__((ext_vector_type(8))) short;
using f32x4  = __attribute__((ext_vector_type(4))) float;

union I8 { int4 v[2]; int s[8]; };
union F8 { float4 v[2]; float s[8]; };

__device__ __forceinline__ unsigned bfpack(float a, float b) {
  __hip_bfloat162 r = __float22bfloat162_rn(make_float2(a, b));
  union { __hip_bfloat162 h; unsigned u; } c; c.h = r; return c.u;
}

// ---------------------------------------------------------------------------
// Kernel 0: mew[i][j] = adj ? bf16(ew) : -0.0  (sign bit = mask).
// |mew| multiplies pew; sign gates the denominator contribution.
// ---------------------------------------------------------------------------
__global__ __launch_bounds__(256) void gat_mask(
    const int* __restrict__ adj, const float* __restrict__ ew,
    unsigned short* __restrict__ mew) {
  const size_t base = ((size_t)blockIdx.x * 256 + threadIdx.x) * 8;
  I8 aj; aj.v[0] = *(const int4*)(adj + base); aj.v[1] = *(const int4*)(adj + base + 4);
  F8 e;  e.v[0]  = *(const float4*)(ew + base); e.v[1]  = *(const float4*)(ew + base + 4);
  union { unsigned short u[8]; uint4 v; } o;
  #pragma unroll
  for (int u = 0; u < 8; ++u) {
    __hip_bfloat16 hb = __float2bfloat16(e.s[u]);
    unsigned short bits = *reinterpret_cast<unsigned short*>(&hb);
    o.u[u] = aj.s[u] ? bits : (unsigned short)0x8000;   // -0.0 when masked
  }
  *(uint4*)(mew + base) = o.v;
}

// ---------------------------------------------------------------------------
// Kernel 1: h = x@W. Emits es (row-major) and edt TRANSPOSED [b][h][j]
// (both pre-scaled by log2e), plus h transposed bf16 hi/lo: h_t[b][f][j].
// ---------------------------------------------------------------------------
__global__ __launch_bounds__(256, 2) void gat_proj(
    const float* __restrict__ x, const float* __restrict__ W,
    const float* __restrict__ a,
    unsigned short* __restrict__ h_hi, unsigned short* __restrict__ h_lo,
    float* __restrict__ es, float* __restrict__ edt) {
  __shared__ float xs[16 * FI];
  const int t = threadIdx.x;
  const int row0 = blockIdx.x * 16;
  for (int i = t; i < 16 * FI; i += 256) xs[i] = x[row0 * FI + i];
  const int f  = t & 127;
  const int rh = t >> 7;              // rows rh*8 .. rh*8+7
  float wc[FI];
  #pragma unroll
  for (int k = 0; k < FI; ++k) wc[k] = W[k * FO + f];
  const int hh = f >> 5, d = f & 31;
  const float a_s = a[hh * 64 + d] * LOG2E;
  const float a_d = a[hh * 64 + 32 + d] * LOG2E;
  __syncthreads();
  float acc8[8];
  #pragma unroll
  for (int r = 0; r < 8; ++r) {
    const int lr = rh * 8 + r;
    const float4* xr = (const float4*)(xs + lr * FI);
    float acc = 0.f;
    #pragma unroll
    for (int kq = 0; kq < FI / 4; ++kq) {
      const float4 xv = xr[kq];
      acc += xv.x * wc[4*kq] + xv.y * wc[4*kq+1] + xv.z * wc[4*kq+2] + xv.w * wc[4*kq+3];
    }
    acc8[r] = acc;
    float ps = acc * a_s, pd = acc * a_d;   // reduce over 32 d-lanes
    #pragma unroll
    for (int off = 16; off; off >>= 1) {
      ps += __shfl_xor(ps, off, 64);
      pd += __shfl_xor(pd, off, 64);
    }
    const int row = row0 + lr;
    if (d == 0) {
      es[row * NH + hh] = ps;
      edt[((size_t)((row >> 10) * NH + hh)) * N + (row & 1023)] = pd;
    }
  }
  // transposed bf16 hi/lo stores: h_t[b][f][j]
  const int bb = row0 >> 10;
  const int jl = (row0 & 1023) + rh * 8;
  union { unsigned short u16[8]; uint4 v; } hi, lo;
  #pragma unroll
  for (int r = 0; r < 8; ++r) {
    __hip_bfloat16 hb = __float2bfloat16(acc8[r]);
    hi.u16[r] = *reinterpret_cast<unsigned short*>(&hb);
    float res = acc8[r] - __bfloat162float(hb);
    __hip_bfloat16 lb = __float2bfloat16(res);
    lo.u16[r] = *reinterpret_cast<unsigned short*>(&lb);
  }
  const size_t base = ((size_t)(bb * FO + f)) * N + jl;
  *(uint4*)(h_hi + base) = hi.v;
  *(uint4*)(h_lo + base) = lo.v;
}

// ---------------------------------------------------------------------------
// Kernel 2: fused attention + avg. 512 threads (8 waves), 16-row i-tiles.
//  chunk loop (8 x 128 j):
//   P1: thread = (il 16 x jq 32), 4 j x 4 h exps -> pew bf16 A-frag LDS
//   P2: wave = (head x f-half): MFMA 16x16x32_bf16, B hi/lo from global h_t
//  epi: denom reduce -> inv; store out; avg pass (mew/edt L1-hot recompute).
// ---------------------------------------------------------------------------
__global__ __launch_bounds__(512, 2) void gat_attn(
    const unsigned short* __restrict__ h_hi, const unsigned short* __restrict__ h_lo,
    const float* __restrict__ es, const float* __restrict__ edt,
    const unsigned short* __restrict__ mew,
    float* __restrict__ out, float* __restrict__ avg) {
  __shared__ unsigned short pew[4 * 2048];   // per-head A-frag tiles, swizzled
  __shared__ float dvl[64];
  const int t  = threadIdx.x;
  const int b  = blockIdx.x & 7;             // b-clustered for h_t L2 locality
  const int i0 = (blockIdx.x >> 3) << 4;
  // P1/avg ids
  const int il = t >> 5, jq = t & 31;
  const int gi = i0 + il;
  float esv[4];
  { const float4 e4 = *(const float4*)(es + ((size_t)b * N + gi) * NH);
    esv[0] = e4.x; esv[1] = e4.y; esv[2] = e4.z; esv[3] = e4.w; }
  // P2 ids
  const int lane = t & 63, wave = t >> 6;
  const int hh = wave & 3, nt = wave >> 2;   // head, f-half
  const int m = lane & 15, kq = lane >> 4;
  f32x4 acc = {0.f, 0.f, 0.f, 0.f};
  float dpart[4] = {0.f, 0.f, 0.f, 0.f};

  for (int c = 0; c < 8; ++c) {
    const int j0 = c * 128;
    const int jb = j0 + jq * 4;
    // ---- P1 ----
    {
      union { uint2 v; unsigned short u[4]; } mwu;
      mwu.v = *(const uint2*)(mew + (size_t)gi * N + jb);
      float mfa[4], sgn[4];
      #pragma unroll
      for (int u = 0; u < 4; ++u) {
        union { unsigned int bb_; float f; } cv;
        cv.bb_ = (unsigned int)(mwu.u[u] & 0x7fff) << 16;
        mfa[u] = cv.f;
        sgn[u] = (mwu.u[u] >> 15) ? 0.f : 1.f;
      }
      float edh[4][4];
      #pragma unroll
      for (int h = 0; h < 4; ++h) {
        const float4 e4 = *(const float4*)(edt + ((size_t)(b * NH + h)) * N + jb);
        edh[h][0] = e4.x; edh[h][1] = e4.y; edh[h][2] = e4.z; edh[h][3] = e4.w;
      }
      float pw[4][4];
      #pragma unroll
      for (int u = 0; u < 4; ++u) {
        #pragma unroll
        for (int h = 0; h < 4; ++h) {
          float e = esv[h] + edh[h][u];
          e = fmaxf(e, 0.2f * e);
          const float p = __builtin_amdgcn_exp2f(e);
          dpart[h] = fmaf(p, sgn[u], dpart[h]);
          pw[h][u] = p * mfa[u];
        }
      }
      const int g = jq >> 1, half = jq & 1;
      const int o = (((g * 16 + il) ^ (g & 7)) * 8) + half * 4;
      #pragma unroll
      for (int h = 0; h < 4; ++h) {
        uint2 pk = { bfpack(pw[h][0], pw[h][1]), bfpack(pw[h][2], pw[h][3]) };
        *(uint2*)(pew + h * 2048 + o) = pk;
      }
    }
    __syncthreads();
    // ---- P2: MFMA, B-frags straight from global (L2-hot h_t) ----
    #pragma unroll
    for (int ks = 0; ks < 4; ++ks) {
      const int g2 = ks * 4 + kq;
      const int o2 = ((g2 * 16 + m) ^ (g2 & 7)) * 8;
      short8 afr;
      { uint4 tmp = *(const uint4*)(pew + hh * 2048 + o2);
        __builtin_memcpy(&afr, &tmp, 16); }
      const int jc = j0 + ks * 32 + kq * 8;
      const size_t boff = ((size_t)(b * FO + hh * 32 + nt * 16 + m)) * N + jc;
      const short8 bhi = *(const short8*)(h_hi + boff);
      const short8 blo = *(const short8*)(h_lo + boff);
      acc = __builtin_amdgcn_mfma_f32_16x16x32_bf16(afr, bhi, acc, 0, 0, 0);
      acc = __builtin_amdgcn_mfma_f32_16x16x32_bf16(afr, blo, acc, 0, 0, 0);
    }
    __syncthreads();
  }

  // ---- denominators: 32 lanes sharing il reduce over jq ----
  #pragma unroll
  for (int h = 0; h < 4; ++h) {
    float v = dpart[h];
    v += __shfl_xor(v, 1, 64);  v += __shfl_xor(v, 2, 64);
    v += __shfl_xor(v, 4, 64);  v += __shfl_xor(v, 8, 64);
    v += __shfl_xor(v, 16, 64);
    if (jq == 0) dvl[il * NH + h] = v;
  }
  __syncthreads();
  if (t < 64) { const float dd = dvl[t]; dvl[t] = dd > 0.f ? 1.0f / dd : 0.f; }
  __syncthreads();
  // ---- epilogue: normalize D, store out ----
  #pragma unroll
  for (int reg = 0; reg < 4; ++reg) {
    const int row = kq * 4 + reg;              // D: col=lane&15, row=quad*4+reg
    const float inv = dvl[row * NH + hh];
    out[((size_t)b * N + i0 + row) * FO + hh * 32 + nt * 16 + m] = acc[reg] * inv;
  }
  // ---- avg pass: recompute p (mew/edt L1-hot), scale by inv ----
  float inv4[4];
  #pragma unroll
  for (int h = 0; h < 4; ++h) inv4[h] = dvl[il * NH + h];
  for (int c = 0; c < 8; ++c) {
    const int jb = c * 128 + jq * 4;
    union { uint2 v; unsigned short u[4]; } mwu;
    mwu.v = *(const uint2*)(mew + (size_t)gi * N + jb);
    float edh[4][4];
    #pragma unroll
    for (int h = 0; h < 4; ++h) {
      const float4 e4 = *(const float4*)(edt + ((size_t)(b * NH + h)) * N + jb);
      edh[h][0] = e4.x; edh[h][1] = e4.y; edh[h][2] = e4.z; edh[h][3] = e4.w;
    }
    float4 r;
    float* rp = &r.x;
    #pragma unroll
    for (int u = 0; u < 4; ++u) {
      union { unsigned int bb_; float f; } cv;
      cv.bb_ = (unsigned int)(mwu.u[u] & 0x7fff) << 16;
      float sv = 0.f;
      #pragma unroll
      for (int h = 0; h < 4; ++h) {
        float e = esv[h] + edh[h][u];
        e = fmaxf(e, 0.2f * e);
        sv += __builtin_amdgcn_exp2f(e) * inv4[h];
      }
      rp[u] = 0.25f * cv.f * sv;               // masked: |mew|=0 -> 0
    }
    *(float4*)(avg + ((size_t)b * N + gi) * N + jb) = r;
  }
}

// ---------------------------------------------------------------------------
extern "C" void kernel_launch(void* const* d_in, const int* in_sizes, int n_in,
                              void* d_out, int out_size, void* d_ws, size_t ws_size,
                              hipStream_t stream) {
  const float* x   = (const float*)d_in[0];
  const int*   adj = (const int*)d_in[1];
  const float* ewt = (const float*)d_in[2];
  const float* W   = (const float*)d_in[3];
  const float* a   = (const float*)d_in[4];

  float* out = (float*)d_out;                  // [B,N,128]
  float* avg = out + (size_t)B * N * FO;       // [B,N,N]

  unsigned short* hhi = (unsigned short*)d_ws;        // [B*FO, N] bf16, 2 MB
  unsigned short* hlo = hhi + (size_t)B * FO * N;     // residual, 2 MB
  unsigned short* mew = hlo + (size_t)B * FO * N;     // [N,N] bf16 masked, 2 MB
  float* es  = (float*)(mew + (size_t)N * N);         // [B*N, 4]
  float* edt = es + (size_t)B * N * NH;               // [B, 4, N]

  gat_mask<<<(N * N) / 2048, 256, 0, stream>>>(adj, ewt, mew);
  gat_proj<<<(B * N) / 16, 256, 0, stream>>>(x, W, a, hhi, hlo, es, edt);
  gat_attn<<<B * (N / 16), 512, 0, stream>>>(hhi, hlo, es, edt, mew, out, avg);
}

// Round 6
// 130.229 us; speedup vs baseline: 1.4688x; 1.0127x over previous
//
#include <hip/hip_runtime.h>
#include <hip/hip_bf16.h>

constexpr int B  = 8;
constexpr int N  = 1024;
constexpr int FI = 64;
constexpr int FO = 128;
constexpr int NH = 4;
constexpr float LOG2E = 1.4426950408889634f;

using short8 = __attribute__((ext_vector_type(8))) short;
using f32x4  = __attribute__((ext_vector_type(4))) float;

union I8 { int4 v[2]; int s[8]; };
union F8 { float4 v[2]; float s[8]; };

__device__ __forceinline__ unsigned bfpack(float a, float b) {
  __hip_bfloat162 r = __float22bfloat162_rn(make_float2(a, b));
  union { __hip_bfloat162 h; unsigned u; } c; c.h = r; return c.u;
}
__device__ __forceinline__ float bf2f(unsigned short u) {
  union { unsigned int b; float f; } c; c.b = (unsigned int)u << 16; return c.f;
}

// ---------------------------------------------------------------------------
// Kernel 0: mew[i][j] = adj ? bf16(ew) : -0.0  (sign bit = mask).
// ---------------------------------------------------------------------------
__global__ __launch_bounds__(256) void gat_mask(
    const int* __restrict__ adj, const float* __restrict__ ew,
    unsigned short* __restrict__ mew) {
  const size_t base = ((size_t)blockIdx.x * 256 + threadIdx.x) * 8;
  I8 aj; aj.v[0] = *(const int4*)(adj + base); aj.v[1] = *(const int4*)(adj + base + 4);
  F8 e;  e.v[0]  = *(const float4*)(ew + base); e.v[1]  = *(const float4*)(ew + base + 4);
  union { unsigned short u[8]; uint4 v; } o;
  #pragma unroll
  for (int u = 0; u < 8; ++u) {
    __hip_bfloat16 hb = __float2bfloat16(e.s[u]);
    unsigned short bits = *reinterpret_cast<unsigned short*>(&hb);
    o.u[u] = aj.s[u] ? bits : (unsigned short)0x8000;   // -0.0 when masked
  }
  *(uint4*)(mew + base) = o.v;
}

// ---------------------------------------------------------------------------
// Kernel 1: h = x@W. Emits es (row-major) + edt transposed [b][h][j] (both
// pre-scaled by log2e), and h transposed bf16 hi/lo: h_t[b][f][j].
// ---------------------------------------------------------------------------
__global__ __launch_bounds__(256, 2) void gat_proj(
    const float* __restrict__ x, const float* __restrict__ W,
    const float* __restrict__ a,
    unsigned short* __restrict__ h_hi, unsigned short* __restrict__ h_lo,
    float* __restrict__ es, float* __restrict__ edt) {
  __shared__ float xs[16 * FI];
  const int t = threadIdx.x;
  const int row0 = blockIdx.x * 16;
  for (int i = t; i < 16 * FI; i += 256) xs[i] = x[row0 * FI + i];
  const int f  = t & 127;
  const int rh = t >> 7;
  float wc[FI];
  #pragma unroll
  for (int k = 0; k < FI; ++k) wc[k] = W[k * FO + f];
  const int hh = f >> 5, d = f & 31;
  const float a_s = a[hh * 64 + d] * LOG2E;
  const float a_d = a[hh * 64 + 32 + d] * LOG2E;
  __syncthreads();
  float acc8[8];
  #pragma unroll
  for (int r = 0; r < 8; ++r) {
    const int lr = rh * 8 + r;
    const float4* xr = (const float4*)(xs + lr * FI);
    float acc = 0.f;
    #pragma unroll
    for (int kq = 0; kq < FI / 4; ++kq) {
      const float4 xv = xr[kq];
      acc += xv.x * wc[4*kq] + xv.y * wc[4*kq+1] + xv.z * wc[4*kq+2] + xv.w * wc[4*kq+3];
    }
    acc8[r] = acc;
    float ps = acc * a_s, pd = acc * a_d;
    #pragma unroll
    for (int off = 16; off; off >>= 1) {
      ps += __shfl_xor(ps, off, 64);
      pd += __shfl_xor(pd, off, 64);
    }
    const int row = row0 + lr;
    if (d == 0) {
      es[row * NH + hh] = ps;
      edt[((size_t)((row >> 10) * NH + hh)) * N + (row & 1023)] = pd;
    }
  }
  const int bb = row0 >> 10;
  const int jl = (row0 & 1023) + rh * 8;
  union { unsigned short u16[8]; uint4 v; } hi, lo;
  #pragma unroll
  for (int r = 0; r < 8; ++r) {
    __hip_bfloat16 hb = __float2bfloat16(acc8[r]);
    hi.u16[r] = *reinterpret_cast<unsigned short*>(&hb);
    float res = acc8[r] - __bfloat162float(hb);
    __hip_bfloat16 lb = __float2bfloat16(res);
    lo.u16[r] = *reinterpret_cast<unsigned short*>(&lb);
  }
  const size_t base = ((size_t)(bb * FO + f)) * N + jl;
  *(uint4*)(h_hi + base) = hi.v;
  *(uint4*)(h_lo + base) = lo.v;
}

// ---------------------------------------------------------------------------
// Kernel 2: fused attention + avg. 512 threads, 16-row i-tiles.
//  Phase A: barrier-free denominator pass (8 chunks, pure load->exp->acc).
//  Phase B: double-buffered chunk loop, 1 barrier/chunk:
//   P2(c): MFMA from pew[c&1] (bf16 p*|mew|, UNnormalized - R4-proven),
//          split hi/lo accumulators, B from global h_t.
//   P1(c+1): exps; avg row = 0.25*sum_h(p*|mew|*inv) in fp32 (R4-proven);
//            bf16 pack p*|mew| -> pew[(c+1)&1].
//  Epilogue: out = (acc_hi + acc_lo) * inv  (fp32 normalization, R4-proven).
// ---------------------------------------------------------------------------
__global__ __launch_bounds__(512, 2) void gat_attn(
    const unsigned short* __restrict__ h_hi, const unsigned short* __restrict__ h_lo,
    const float* __restrict__ es, const float* __restrict__ edt,
    const unsigned short* __restrict__ mew,
    float* __restrict__ out, float* __restrict__ avg) {
  __shared__ unsigned short pew[2][4 * 2048];   // double-buffered A-frag tiles
  __shared__ float dvl[64];
  const int t  = threadIdx.x;
  const int b  = blockIdx.x & 7;
  const int i0 = (blockIdx.x >> 3) << 4;
  // P1 ids
  const int il = t >> 5, jq = t & 31;
  const int gi = i0 + il;
  float esv[4];
  { const float4 e4 = *(const float4*)(es + ((size_t)b * N + gi) * NH);
    esv[0] = e4.x; esv[1] = e4.y; esv[2] = e4.z; esv[3] = e4.w; }
  // P2 ids
  const int lane = t & 63, wave = t >> 6;
  const int hh = wave & 3, nt2 = wave >> 2;
  const int m = lane & 15, kq = lane >> 4;
  f32x4 acch = {0.f,0.f,0.f,0.f}, accl = {0.f,0.f,0.f,0.f};

  // ---- Phase A: denominators, no barriers ----
  float dpart[4] = {0.f, 0.f, 0.f, 0.f};
  #pragma unroll 2
  for (int c = 0; c < 8; ++c) {
    const int jb = c * 128 + jq * 4;
    union { uint2 v; unsigned short u[4]; } mwu;
    mwu.v = *(const uint2*)(mew + (size_t)gi * N + jb);
    float edh[4][4];
    #pragma unroll
    for (int h = 0; h < 4; ++h) {
      const float4 e4 = *(const float4*)(edt + ((size_t)(b * NH + h)) * N + jb);
      edh[h][0] = e4.x; edh[h][1] = e4.y; edh[h][2] = e4.z; edh[h][3] = e4.w;
    }
    #pragma unroll
    for (int u = 0; u < 4; ++u) {
      const float sgn = (mwu.u[u] >> 15) ? 0.f : 1.f;
      #pragma unroll
      for (int h = 0; h < 4; ++h) {
        float e = esv[h] + edh[h][u];
        e = fmaxf(e, 0.2f * e);
        dpart[h] = fmaf(__builtin_amdgcn_exp2f(e), sgn, dpart[h]);
      }
    }
  }
  #pragma unroll
  for (int h = 0; h < 4; ++h) {
    float v = dpart[h];
    v += __shfl_xor(v, 1, 64);  v += __shfl_xor(v, 2, 64);
    v += __shfl_xor(v, 4, 64);  v += __shfl_xor(v, 8, 64);
    v += __shfl_xor(v, 16, 64);
    if (jq == 0) dvl[il * NH + h] = v;
  }
  __syncthreads();
  if (t < 64) { const float dd = dvl[t]; dvl[t] = dd > 0.f ? 1.0f / dd : 0.f; }
  __syncthreads();
  float inv4[4];
  #pragma unroll
  for (int h = 0; h < 4; ++h) inv4[h] = dvl[il * NH + h];

  // ---- Phase B helpers ----
  auto p1_step = [&](int c, int buf) {
    const int jb = c * 128 + jq * 4;
    union { uint2 v; unsigned short u[4]; } mwu;
    mwu.v = *(const uint2*)(mew + (size_t)gi * N + jb);
    float edh[4][4];
    #pragma unroll
    for (int h = 0; h < 4; ++h) {
      const float4 e4 = *(const float4*)(edt + ((size_t)(b * NH + h)) * N + jb);
      edh[h][0] = e4.x; edh[h][1] = e4.y; edh[h][2] = e4.z; edh[h][3] = e4.w;
    }
    float pw[4][4];       // p * |mew|  (unnormalized, goes to bf16 pew)
    float4 r;
    float* rp = &r.x;
    #pragma unroll
    for (int u = 0; u < 4; ++u) {
      const float mfa = bf2f((unsigned short)(mwu.u[u] & 0x7fff));
      float sv = 0.f;
      #pragma unroll
      for (int h = 0; h < 4; ++h) {
        float e = esv[h] + edh[h][u];
        e = fmaxf(e, 0.2f * e);
        const float p = __builtin_amdgcn_exp2f(e);
        pw[h][u] = p * mfa;
        sv += p * inv4[h];
      }
      rp[u] = 0.25f * mfa * sv;     // fp32 avg (R4-proven formula)
    }
    *(float4*)(avg + ((size_t)b * N + gi) * N + jb) = r;
    const int g = jq >> 1, half = jq & 1;
    const int o = (((g * 16 + il) ^ (g & 7)) * 8) + half * 4;
    #pragma unroll
    for (int h = 0; h < 4; ++h) {
      uint2 pk = { bfpack(pw[h][0], pw[h][1]), bfpack(pw[h][2], pw[h][3]) };
      *(uint2*)(pew[buf] + h * 2048 + o) = pk;
    }
  };
  auto p2_step = [&](int c, int buf) {
    const int j0 = c * 128;
    #pragma unroll
    for (int ks = 0; ks < 4; ++ks) {
      const int g2 = ks * 4 + kq;
      const int o2 = ((g2 * 16 + m) ^ (g2 & 7)) * 8;
      short8 afr;
      { uint4 tmp = *(const uint4*)(pew[buf] + hh * 2048 + o2);
        __builtin_memcpy(&afr, &tmp, 16); }
      const int jc = j0 + ks * 32 + kq * 8;
      const size_t boff = ((size_t)(b * FO + hh * 32 + nt2 * 16 + m)) * N + jc;
      const short8 bhi = *(const short8*)(h_hi + boff);
      const short8 blo = *(const short8*)(h_lo + boff);
      acch = __builtin_amdgcn_mfma_f32_16x16x32_bf16(afr, bhi, acch, 0, 0, 0);
      accl = __builtin_amdgcn_mfma_f32_16x16x32_bf16(afr, blo, accl, 0, 0, 0);
    }
  };

  // ---- Phase B: double-buffered pipeline, 1 barrier per chunk ----
  p1_step(0, 0);
  __syncthreads();
  for (int c = 0; c < 8; ++c) {
    if (c + 1 < 8) p1_step(c + 1, (c + 1) & 1);
    p2_step(c, c & 1);
    if (c + 1 < 8) __syncthreads();
  }

  // ---- epilogue: out = (acc_hi + acc_lo) * inv  (fp32 normalization) ----
  #pragma unroll
  for (int reg = 0; reg < 4; ++reg) {
    const int row = kq * 4 + reg;              // D: col=lane&15, row=quad*4+reg
    const float inv = dvl[row * NH + hh];
    out[((size_t)b * N + i0 + row) * FO + hh * 32 + nt2 * 16 + m]
        = (acch[reg] + accl[reg]) * inv;
  }
}

// ---------------------------------------------------------------------------
extern "C" void kernel_launch(void* const* d_in, const int* in_sizes, int n_in,
                              void* d_out, int out_size, void* d_ws, size_t ws_size,
                              hipStream_t stream) {
  const float* x   = (const float*)d_in[0];
  const int*   adj = (const int*)d_in[1];
  const float* ewt = (const float*)d_in[2];
  const float* W   = (const float*)d_in[3];
  const float* a   = (const float*)d_in[4];

  float* out = (float*)d_out;                  // [B,N,128]
  float* avg = out + (size_t)B * N * FO;       // [B,N,N]

  unsigned short* hhi = (unsigned short*)d_ws;        // [B*FO, N] bf16, 2 MB
  unsigned short* hlo = hhi + (size_t)B * FO * N;     // residual, 2 MB
  unsigned short* mew = hlo + (size_t)B * FO * N;     // [N,N] bf16 masked, 2 MB
  float* es  = (float*)(mew + (size_t)N * N);         // [B*N, 4]
  float* edt = es + (size_t)B * N * NH;               // [B, 4, N]

  gat_mask<<<(N * N) / 2048, 256, 0, stream>>>(adj, ewt, mew);
  gat_proj<<<(B * N) / 16, 256, 0, stream>>>(x, W, a, hhi, hlo, es, edt);
  gat_attn<<<B * (N / 16), 512, 0, stream>>>(hhi, hlo, es, edt, mew, out, avg);
}